// Round 5
// baseline (191.235 us; speedup 1.0000x reference)
//
#include <hip/hip_runtime.h>

#define S_DIM 4096
#define H_DIM 16
#define D_DIM 64
#define N_BLK 64          // S / 64 query blocks
#define NEG_INF_F (-1e30f)
#define QSCALE 0.125f     // 1/sqrt(64), exact

typedef __attribute__((ext_vector_type(4))) float f32x4;
typedef __attribute__((ext_vector_type(8))) short s16x8;
typedef __attribute__((ext_vector_type(4))) unsigned int u32x4;
typedef __attribute__((ext_vector_type(2))) unsigned int u32x2;

__device__ __forceinline__ unsigned int fbits(float f) {
    return __builtin_bit_cast(unsigned int, f);
}
// pack two floats -> two bf16 (round-half-up; inputs never NaN here). lo=a, hi=b
__device__ __forceinline__ unsigned int pkbf(float a, float b) {
    return __builtin_amdgcn_perm(fbits(b) + 0x8000u, fbits(a) + 0x8000u, 0x07060302u);
}

// SPLIT-K structure. Total problem parallelism with 1 wave per query block is
// B*H*N = 2048 waves = 2 waves/SIMD chip-wide -> every pipe <25% busy
// (latency-bound; R0's counters). Fix: TWO waves per query block, split by KEY
// tiles (wave A: j = n-2..n, wave B: j = n+1..n+2), merged at the end. This
// preserves the 4 independent qt softmax chains per wave (R2's qt-split halved
// that ILP and regressed) and duplicates no K loads. 4096 waves = 4/SIMD.
// Block = 8 waves (512 thr) = 4 query blocks x 2 split-K waves; V^T LDS (64KB,
// 8 tiles) shared as in R0; grid 512 blocks = exactly 2 blocks/CU = 16
// waves/CU. 4 waves/SIMD requires VGPR <= 128 -> __launch_bounds__(512,2)
// (empirical hipcc cap = 256/min_waves_arg: (512,4)->64 spilled, (256,2)->128
// ok at 120 used, (256,1)->256). Main loop kept EXACTLY R0's (fully-unrolled
// continue-guarded loop; R4's rolled+prefetch variant regressed).
// Merge (reuses dead lds_vt): exchange m,l; each wave scales its partial O by
// exp(m_own - m_merged); exchange scaled partials (dt-major so b128 LDS ops
// are lane-contiguous); wave A finalizes qt0,1, wave B qt2,3.
// V^T LDS layout: row d (0..63), 512 keys as 256 u32 bf16-pairs, column
// ROTATED by 8*d shorts (mod 512) to spread banks (R2's 512-thread staging
// mapping: per-32-lane phase has uniform d, 32 distinct banks; measured 0
// conflicts).
__global__ __launch_bounds__(512, 2) void bsattn_kernel(
    const float* __restrict__ qg, const float* __restrict__ kg,
    const float* __restrict__ vg, float* __restrict__ outg)
{
    __shared__ unsigned int lds_vt[D_DIM * 256];   // 64 KB: V^T bf16 pairs, rotated

    const int tid  = threadIdx.x;
    const int w    = tid >> 6;                   // 0..7
    const int lane = tid & 63;
    const int quad = lane >> 4;
    const int l16  = lane & 15;

    const int b    = blockIdx.z;
    const int h    = blockIdx.y;
    const int n0   = blockIdx.x << 2;
    const int p    = w >> 1;                     // query-block pair index 0..3
    const int wsub = w & 1;                      // 0: key tiles t=0..2, 1: t=3..4
    const int n    = n0 + p;                     // this wave's query block

    // ---- Q fragments (B-operand): bq[qt][hh], pre-scaled, bf16 ----
    s16x8 bq[4][2];
#pragma unroll
    for (int qt = 0; qt < 4; ++qt) {
        const size_t qrow = ((size_t)(b * S_DIM + n * 64 + qt * 16 + l16) * H_DIM + h) * D_DIM;
#pragma unroll
        for (int hh = 0; hh < 2; ++hh) {
            const float4* qp = reinterpret_cast<const float4*>(qg + qrow + hh * 32 + quad * 8);
            float4 f0 = qp[0];
            float4 f1 = qp[1];
            u32x4 u;
            u.x = pkbf(f0.x * QSCALE, f0.y * QSCALE);
            u.y = pkbf(f0.z * QSCALE, f0.w * QSCALE);
            u.z = pkbf(f1.x * QSCALE, f1.y * QSCALE);
            u.w = pkbf(f1.z * QSCALE, f1.w * QSCALE);
            bq[qt][hh] = __builtin_bit_cast(s16x8, u);
        }
    }

    // ---- V^T staging: wave w stages tile w; lane -> (row-pair sp, d-half dh) ----
    {
        const int jt = w;                        // 0..7 tile (wave-uniform)
        const int sp = lane & 31;                // row-pair index
        const int dh = lane >> 5;                // d-half (0: d<32, 1: d>=32)
        const int jv = n0 - 2 + jt;
        if (jv >= 0 && jv < N_BLK) {
            const float* v0p = vg + ((size_t)(b * S_DIM + jv * 64 + 2 * sp) * H_DIM + h) * D_DIM;
            const float* v1p = v0p + H_DIM * D_DIM;
            const int craw = jt * 64 + 2 * sp;   // raw column (key index) of this pair
#pragma unroll
            for (int ch = 0; ch < 2; ++ch) {     // 16 d-values per chunk
                const int d0 = dh * 32 + ch * 16;
                const float4* ap = reinterpret_cast<const float4*>(v0p + d0);
                const float4* bp = reinterpret_cast<const float4*>(v1p + d0);
                float4 a0 = ap[0], a1 = ap[1], a2 = ap[2], a3 = ap[3];
                float4 b0 = bp[0], b1 = bp[1], b2 = bp[2], b3 = bp[3];
                float av[16] = {a0.x,a0.y,a0.z,a0.w, a1.x,a1.y,a1.z,a1.w,
                                a2.x,a2.y,a2.z,a2.w, a3.x,a3.y,a3.z,a3.w};
                float bv[16] = {b0.x,b0.y,b0.z,b0.w, b1.x,b1.y,b1.z,b1.w,
                                b2.x,b2.y,b2.z,b2.w, b3.x,b3.y,b3.z,b3.w};
#pragma unroll
                for (int i = 0; i < 16; ++i) {
                    const int d = d0 + i;
                    lds_vt[d * 256 + (((craw + 8 * d) & 511) >> 1)] = pkbf(av[i], bv[i]);
                }
            }
        }
    }

    f32x4 o[4][4];                   // partial O accum [qt][dt] (row=query, col=d)
    float m_run[4], l_run[4];
#pragma unroll
    for (int qt = 0; qt < 4; ++qt) {
        m_run[qt] = NEG_INF_F; l_run[qt] = 0.f;
#pragma unroll
        for (int dt = 0; dt < 4; ++dt) o[qt][dt] = (f32x4){0.f, 0.f, 0.f, 0.f};
    }

    __syncthreads();                 // V^T visible; barrier-free main loop

    const int colb = quad * 4 + 8 * l16;     // read-column base (rotation part w/o tile/dt)

    for (int t = 0; t < 5; ++t) {
        if (wsub ? (t < 3) : (t >= 3)) continue;   // split-K: A owns t=0..2, B owns t=3..4
        const int j = n - 2 + t;             // key block (wave-uniform)
        if (j < 0 || j >= N_BLK) continue;
        const int ji = p + t;                // staged tile index = j - n0 + 2

        // ---- K A-fragments direct from global (coalesced 16-row x 128B chunks) ----
        float4 kf[4][2][2];
#pragma unroll
        for (int kt = 0; kt < 4; ++kt) {
            const size_t krow = ((size_t)(b * S_DIM + j * 64 + kt * 16 + l16) * H_DIM + h) * D_DIM + quad * 8;
#pragma unroll
            for (int hh = 0; hh < 2; ++hh) {
                const float4* kp = reinterpret_cast<const float4*>(kg + krow + hh * 32);
                kf[kt][hh][0] = kp[0];
                kf[kt][hh][1] = kp[1];
            }
        }
        s16x8 kbf[4][2];
#pragma unroll
        for (int kt = 0; kt < 4; ++kt)
#pragma unroll
            for (int hh = 0; hh < 2; ++hh) {
                u32x4 u;
                u.x = pkbf(kf[kt][hh][0].x, kf[kt][hh][0].y);
                u.y = pkbf(kf[kt][hh][0].z, kf[kt][hh][0].w);
                u.z = pkbf(kf[kt][hh][1].x, kf[kt][hh][1].y);
                u.w = pkbf(kf[kt][hh][1].z, kf[kt][hh][1].w);
                kbf[kt][hh] = __builtin_bit_cast(s16x8, u);
            }

        // ---- per qt: S^T = K x Q^T, online softmax; P stays in registers ----
        s16x8 pa[4][2];
#pragma unroll
        for (int qt = 0; qt < 4; ++qt) {
            f32x4 sa[4];
#pragma unroll
            for (int kt = 0; kt < 4; ++kt) {
                f32x4 z = {0.f, 0.f, 0.f, 0.f};
                f32x4 a0 = __builtin_amdgcn_mfma_f32_16x16x32_bf16(kbf[kt][0], bq[qt][0], z, 0, 0, 0);
                sa[kt]   = __builtin_amdgcn_mfma_f32_16x16x32_bf16(kbf[kt][1], bq[qt][1], a0, 0, 0, 0);
            }
            float mx = NEG_INF_F;
#pragma unroll
            for (int kt = 0; kt < 4; ++kt)
#pragma unroll
                for (int r = 0; r < 4; ++r) mx = fmaxf(mx, sa[kt][r]);
            mx = fmaxf(mx, __shfl_xor(mx, 16));
            mx = fmaxf(mx, __shfl_xor(mx, 32));
            const float mn = fmaxf(m_run[qt], mx);
            const float alpha = __expf(m_run[qt] - mn);
            m_run[qt] = mn;

            float rs = 0.f;
            unsigned int pk[4][2];
#pragma unroll
            for (int kt = 0; kt < 4; ++kt) {
                float e0 = __expf(sa[kt][0] - mn);
                float e1 = __expf(sa[kt][1] - mn);
                float e2 = __expf(sa[kt][2] - mn);
                float e3 = __expf(sa[kt][3] - mn);
                rs += (e0 + e1) + (e2 + e3);
                pk[kt][0] = pkbf(e0, e1);
                pk[kt][1] = pkbf(e2, e3);
            }
            rs += __shfl_xor(rs, 16);
            rs += __shfl_xor(rs, 32);
            l_run[qt] = l_run[qt] * alpha + rs;

            float ab[4];
#pragma unroll
            for (int r = 0; r < 4; ++r)
                ab[r] = __shfl(alpha, (lane & 48) + quad * 4 + r);
#pragma unroll
            for (int dt = 0; dt < 4; ++dt)
#pragma unroll
                for (int r = 0; r < 4; ++r) o[qt][dt][r] *= ab[r];

            pa[qt][0] = __builtin_bit_cast(s16x8, (u32x4){pk[0][0], pk[0][1], pk[1][0], pk[1][1]});
            pa[qt][1] = __builtin_bit_cast(s16x8, (u32x4){pk[2][0], pk[2][1], pk[3][0], pk[3][1]});
        }

        // ---- PV: O += P x V (B-frags from rotated V^T LDS, permuted key order) ----
        const int cb0 = ji * 64 + colb;
#pragma unroll
        for (int dt = 0; dt < 4; ++dt) {
            const int d = dt * 16 + l16;
            const unsigned int* vrow = lds_vt + d * 256;
            const int cb = cb0 + 128 * dt;
            u32x2 v00 = *reinterpret_cast<const u32x2*>(vrow + (((cb     ) & 511) >> 1));
            u32x2 v01 = *reinterpret_cast<const u32x2*>(vrow + (((cb + 16) & 511) >> 1));
            u32x2 v10 = *reinterpret_cast<const u32x2*>(vrow + (((cb + 32) & 511) >> 1));
            u32x2 v11 = *reinterpret_cast<const u32x2*>(vrow + (((cb + 48) & 511) >> 1));
            s16x8 vf0 = __builtin_bit_cast(s16x8, (u32x4){v00.x, v00.y, v01.x, v01.y});
            s16x8 vf1 = __builtin_bit_cast(s16x8, (u32x4){v10.x, v10.y, v11.x, v11.y});
#pragma unroll
            for (int qt = 0; qt < 4; ++qt) {
                o[qt][dt] = __builtin_amdgcn_mfma_f32_16x16x32_bf16(pa[qt][0], vf0, o[qt][dt], 0, 0, 0);
                o[qt][dt] = __builtin_amdgcn_mfma_f32_16x16x32_bf16(pa[qt][1], vf1, o[qt][dt], 0, 0, 0);
            }
        }
    }

    // ================= split-K merge (reuses dead lds_vt) =================
    __syncthreads();                                   // all PV reads of V^T done
    float* lbuf = reinterpret_cast<float*>(lds_vt);

    // phase 1: exchange m,l. [pair][half][qt][l16][2] floats (4 KB).
    if (quad == 0) {
#pragma unroll
        for (int qt = 0; qt < 4; ++qt) {
            const int base = ((((p << 1) + wsub) * 4 + qt) * 16 + l16) * 2;
            lbuf[base]     = m_run[qt];
            lbuf[base + 1] = l_run[qt];
        }
    }
    __syncthreads();

    // read partner m,l; merged m = max; s_own = exp(m_own - m); merged l for my qts.
    // Empty-partner case (n=63 wave B): mP=-1e30, lP=0 -> sP=0, contributes 0.
    const int qm0 = wsub << 1;                         // qts I finalize
    float s_own[4];
    float lmv[2];
#pragma unroll
    for (int qt = 0; qt < 4; ++qt) {
        const int pb = ((((p << 1) + (wsub ^ 1)) * 4 + qt) * 16 + l16) * 2;
        const float mP = lbuf[pb], lP = lbuf[pb + 1];
        const float mm = fmaxf(m_run[qt], mP);
        s_own[qt] = __expf(m_run[qt] - mm);
        const float lmt = l_run[qt] * s_own[qt] + lP * __expf(mP - mm);
        if ((qt >> 1) == wsub) lmv[qt & 1] = lmt;
    }
    __syncthreads();                                   // ml reads done before overwrite

    // phase 2: write my OUTGOING scaled partials (the 2 qts my partner finalizes).
    // Layout [pair][qt][dt][lane] f32x4 -> lane-contiguous b128 ops (64 KB exact).
    const int qo0 = (wsub ^ 1) << 1;
#pragma unroll
    for (int qq = 0; qq < 2; ++qq) {
        const int qt = qo0 + qq;
        float sr[4];
#pragma unroll
        for (int r = 0; r < 4; ++r)
            sr[r] = __shfl(s_own[qt], (lane & 48) + quad * 4 + r);
#pragma unroll
        for (int dt = 0; dt < 4; ++dt) {
            f32x4 sv;
#pragma unroll
            for (int r = 0; r < 4; ++r) sv[r] = o[qt][dt][r] * sr[r];
            *reinterpret_cast<f32x4*>(lbuf + ((((p << 2) + qt) * 4 + dt) * 64 + lane) * 4) = sv;
        }
    }
    __syncthreads();

    // phase 3: merge my qts (own scaled + partner's scaled), normalize, store.
#pragma unroll
    for (int qq = 0; qq < 2; ++qq) {
        const int qt = qm0 + qq;
        const float invl = 1.0f / lmv[qq];
        float sr[4], ir[4];
#pragma unroll
        for (int r = 0; r < 4; ++r) {
            const int src = (lane & 48) + quad * 4 + r;
            sr[r] = __shfl(s_own[qt], src);
            ir[r] = __shfl(invl, src);
        }
        f32x4 res[4];
#pragma unroll
        for (int dt = 0; dt < 4; ++dt) {
            const f32x4 oth = *reinterpret_cast<const f32x4*>(
                lbuf + ((((p << 2) + qt) * 4 + dt) * 64 + lane) * 4);
#pragma unroll
            for (int r = 0; r < 4; ++r)
                res[dt][r] = (o[qt][dt][r] * sr[r] + oth[r]) * ir[r];
        }
#pragma unroll
        for (int r = 0; r < 4; ++r) {
            const int row = n * 64 + qt * 16 + quad * 4 + r;
            float* op = outg + ((size_t)(b * S_DIM + row) * H_DIM + h) * D_DIM + l16;
#pragma unroll
            for (int dt = 0; dt < 4; ++dt)
                op[dt * 16] = res[dt][r];
        }
    }
}

extern "C" void kernel_launch(void* const* d_in, const int* in_sizes, int n_in,
                              void* d_out, int out_size, void* d_ws, size_t ws_size,
                              hipStream_t stream) {
    const float* q = (const float*)d_in[0];
    const float* k = (const float*)d_in[1];
    const float* v = (const float*)d_in[2];
    float* out = (float*)d_out;
    const int B = in_sizes[0] / (S_DIM * H_DIM * D_DIM);   // = 2
    dim3 grid(N_BLK / 4, H_DIM, B);
    dim3 block(512);
    hipLaunchKernelGGL(bsattn_kernel, grid, block, 0, stream, q, k, v, out);
}